// Round 1
// baseline (43.789 us; speedup 1.0000x reference)
//
#include <hip/hip_runtime.h>

// DimensionAdaptivePoolingForImages: input (32,64,64,512) f32 NHWC.
// resize is identity (64>=8, 64>=6). Adaptive max pool into 8x6 bins.
// Row bins: uniform 8 rows. Col bins: edges (i*64+3)/6 = {0,11,21,32,43,53,64}
// (matches fp32 round-half-even of i*(64/6) for all i).
// out[b, (iw*6+ih)*512 + m] = max over rows/cols of bin.

__device__ __forceinline__ float4 max4(float4 a, float4 b) {
    return make_float4(fmaxf(a.x, b.x), fmaxf(a.y, b.y),
                       fmaxf(a.z, b.z), fmaxf(a.w, b.w));
}

__global__ __launch_bounds__(128) void dap_pool_kernel(
        const float4* __restrict__ x,   // (32,64,64,128) as float4
        float4* __restrict__ out) {     // (32,48,128) as float4
    const int t   = threadIdx.x;        // 0..127 : float4 channel group
    const int bin = blockIdx.x;         // 0..47  : iw*6 + ih
    const int b   = blockIdx.y;         // 0..31

    const int iw = bin / 6;
    const int ih = bin - iw * 6;
    const int r1 = iw * 8;
    const int c1 = (ih * 64 + 3) / 6;
    const int c2 = ((ih + 1) * 64 + 3) / 6;
    const int nc = c2 - c1;             // 10 or 11 (block-uniform)

    // pixel stride in float4 units = 512/4 = 128
    const float4* base = x + (((size_t)b * 64 + r1) * 64 + c1) * 128 + t;

    const float NEG_INF = -__builtin_inff();
    float4 acc0 = make_float4(NEG_INF, NEG_INF, NEG_INF, NEG_INF);
    float4 acc1 = acc0;

    #pragma unroll
    for (int r = 0; r < 8; ++r) {
        const float4* rowp = base + (size_t)r * 64 * 128;
        #pragma unroll
        for (int c = 0; c < 10; c += 2) {
            acc0 = max4(acc0, rowp[(size_t)c * 128]);
            acc1 = max4(acc1, rowp[(size_t)(c + 1) * 128]);
        }
        if (nc == 11) {                 // block-uniform branch, no divergence
            acc0 = max4(acc0, rowp[(size_t)10 * 128]);
        }
    }
    acc0 = max4(acc0, acc1);

    out[((size_t)b * 48 + bin) * 128 + t] = acc0;
}

extern "C" void kernel_launch(void* const* d_in, const int* in_sizes, int n_in,
                              void* d_out, int out_size, void* d_ws, size_t ws_size,
                              hipStream_t stream) {
    const float4* x = (const float4*)d_in[0];
    float4* out = (float4*)d_out;
    dim3 grid(48, 32);
    dim3 block(128);
    dap_pool_kernel<<<grid, block, 0, stream>>>(x, out);
}